// Round 6
// baseline (267.546 us; speedup 1.0000x reference)
//
#include <hip/hip_runtime.h>
#include <math.h>

#define L 4096
#define B 8
#define D 1024
#define NH 16
#define COUT 256              // output chunk per block; windback amort 1.5x
#define WB 128                // windback length (q^128 <= 2.4e-6 worst-case)
#define NCHUNK (L / COUT)     // 16
#define BD 8192               // B*D floats between consecutive l
#define DBLK 128              // d-values per block
#define TL 16                 // l-rows per LDS tile (8KB)
#define NBUF 4                // quad-buffered, 3 tiles in flight

#define REP4(F) F(0) F(1) F(2) F(3)

typedef float f2 __attribute__((ext_vector_type(2)));

__device__ __forceinline__ float sigmoidf(float v) {
    return 1.0f / (1.0f + __expf(-v));
}

// ---- packed-f32 head math: 8 heads/thread = 4 v_pk_fma_f32 chains ----
// (gfx950 VOP3P packed fp32 is full-rate: the 157.3 TF fp32 vector peak is
// 2x the 78.6 TF fp64 peak precisely via v_pk_fma_f32. This halves FMA issue
// slots; R5 analysis showed issue work ~43us of the 103us wall.)
#define UPD(i) s##i = __builtin_elementwise_fma(q##i, s##i, xv2);
#define UPDALL UPD(0) UPD(1) UPD(2) UPD(3)
#define ACC(i) s##i = __builtin_elementwise_fma(q##i, s##i, xv2); \
               y2 = __builtin_elementwise_fma(P##i, s##i, y2);
#define ACCALL ACC(0) ACC(1) ACC(2) ACC(3)

// async global->LDS, 16B/lane, block-wide tile: wave wv stages rows
// 4wv..4wv+3 (2 instrs x 2 rows x 512B contiguous per row pair).
#define GLD16(g, l) __builtin_amdgcn_global_load_lds( \
    (const __attribute__((address_space(1))) unsigned int*)(g), \
    (__attribute__((address_space(3))) unsigned int*)(l), 16, 0, 0)

#define VM(n) asm volatile("s_waitcnt vmcnt(" #n ")" ::: "memory")
#define MEMFENCE asm volatile("" ::: "memory")

// ---------------------------------------------------------------------------
// Round 6: R5's schedule (block-wide staging, raw s_barrier, EXACT counted
// vmcnt) with the per-head math rewritten in packed fp32. R5 established:
//   - VALUBusy 40% == predicted duty for the actual instruction stream
//     (kernel ~half issue-bound, half stall-bound; d_wall/d_issue ~ 0.5-1)
//   - schedule variants are exhausted (103-117us across 3 structures)
// This round cuts issue: UPD 8 FMA -> 4 pk, ACC 16 FMA -> 8 pk, y-init
// folded into a pk pair. Everything else byte-identical to R5, including
// the vmcnt ladder (loads/stores counts unchanged):
//   windback:       VM(4)
//   output r=0/1/2: VM(4)/VM(20)/VM(36)
//   output r=3..13: VM(52)   (steady: 3x2 loads + 3x16 stores outstanding)
//   output r=14/15: VM(50)/VM(48)
// ---------------------------------------------------------------------------
__global__ void __launch_bounds__(256, 4)
ema_fused(const float* __restrict__ x,
          const float* __restrict__ damp,
          const float* __restrict__ decay,
          const float* __restrict__ ema,
          const float* __restrict__ proj,
          const float* __restrict__ rw,
          float* __restrict__ out) {
    const int tid  = threadIdx.x;
    const int lane = tid & 63;
    const int wv   = tid >> 6;            // wave in block: 0..3
    const int h    = lane & 1;            // head half: 0 -> heads 0-7, 1 -> 8-15
    const int dloc = (wv << 5) + (lane >> 1);   // 0..127: d within block
    const int d    = blockIdx.x * DBLK + dloc;
    const int c    = blockIdx.y;          // 0..NCHUNK-1
    const int b    = blockIdx.z;          // 0..7

    __shared__ float lds[NBUF][TL * DBLK];   // 4 x 8KB = 32KB

    const float* dp = damp  + d * NH + h * 8;
    const float* dc = decay + d * NH + h * 8;
    const float* de = ema   + d * NH + h * 8;
    const float* pj = proj  + d * NH + h * 8;

    // ---- per-head state (packed pairs) + projection weights ----
#define DECLQS(i) f2 q##i, s##i;
    REP4(DECLQS)
#define INITQS(i) { \
        q##i.x = 1.0f - sigmoidf(dp[2*(i)])   * sigmoidf(dc[2*(i)]); \
        q##i.y = 1.0f - sigmoidf(dp[2*(i)+1]) * sigmoidf(dc[2*(i)+1]); \
        s##i.x = 0.0f; s##i.y = 0.0f; }
    REP4(INITQS)
#define DECLP(i) f2 P##i;
    REP4(DECLP)
#define INITP(i) { \
        P##i.x = sigmoidf(dp[2*(i)])   * de[2*(i)]   * pj[2*(i)]   * 0.25f; \
        P##i.y = sigmoidf(dp[2*(i)+1]) * de[2*(i)+1] * pj[2*(i)+1] * 0.25f; }
    REP4(INITP)
    // Even lane of pair adds residual; odd contributes 0; xor-1 combine gives
    // both lanes the identical full result y_conv + x*w.
    const float weff = (h == 0) ? rw[d] : 0.0f;

    // drain parameter loads so the GLD queue accounting below is exact
    VM(0); MEMFENCE;

    const int wb = (c > 0) ? WB : 0;
    const int wt = wb / TL;               // 8 or 0 windback tiles
    const int nt = wt + COUT / TL;        // 24 or 16 tiles total

    // block x base (windback start); per-lane staging src:
    // instr covers 2 rows x 128 floats: row = 4wv + (lane>>5), col = (lane&31)*4
    const float* xb = x + (size_t)(c * COUT - wb) * BD + (size_t)b * D
                        + (size_t)blockIdx.x * DBLK;
    const float* gsrc = xb + (size_t)((wv << 2) + (lane >> 5)) * BD
                           + ((lane & 31) << 2);

#define GLD(t) { \
        const float* g_ = gsrc + (size_t)(t) * (TL * BD); \
        float* l_ = &lds[(t) & 3][(wv << 2) * DBLK]; \
        GLD16(g_, l_); \
        GLD16(g_ + 2 * (size_t)BD, l_ + 2 * DBLK); }

    // ---- prologue: 3 tiles in flight ----
    GLD(0) GLD(1) GLD(2)
    MEMFENCE;

    // ---- windback: state update only (no stores -> VM(4) exact) ----
    if (c > 0) {
        for (int t = 0; t < WB / TL; ++t) {
            VM(4);
            __builtin_amdgcn_s_barrier();
            MEMFENCE;
            GLD(t + 3)
            MEMFENCE;
            const float* bp = &lds[t & 3][dloc];
#pragma unroll
            for (int sl = 0; sl < TL; ++sl) {
                float xv = bp[sl * DBLK];
                f2 xv2; xv2.x = xv; xv2.y = xv;
                UPDALL
            }
        }
    }

    // ---- output phase: 16 tiles ----
    float* opb = out + (size_t)(c * COUT) * BD + (size_t)b * D + d;

#define OTILE(r, KWAIT, DOGLD) { \
        KWAIT; \
        __builtin_amdgcn_s_barrier(); \
        MEMFENCE; \
        if (DOGLD) GLD(wt + (r) + 3) \
        MEMFENCE; \
        const float* bp = &lds[(wt + (r)) & 3][dloc]; \
        float* op = opb + (size_t)(r) * (TL * BD); \
        _Pragma("unroll") \
        for (int sl = 0; sl < TL; ++sl) { \
            float xv = bp[sl * DBLK]; \
            f2 xv2; xv2.x = xv; xv2.y = xv; \
            f2 y2;  y2.x = xv * weff; y2.y = 0.0f; \
            ACCALL \
            float y = y2.x + y2.y; \
            y += __shfl_xor(y, 1); \
            __builtin_nontemporal_store(fmaxf(y, 0.0f), op + (size_t)sl * BD); \
        } }

    OTILE(0,  VM(4),  1)
    OTILE(1,  VM(20), 1)
    OTILE(2,  VM(36), 1)
#pragma unroll
    for (int r = 3; r <= 12; ++r) { OTILE(r, VM(52), 1) }
    OTILE(13, VM(52), 0)
    OTILE(14, VM(50), 0)
    OTILE(15, VM(48), 0)
}

// ---------------------------------------------------------------------------
extern "C" void kernel_launch(void* const* d_in, const int* in_sizes, int n_in,
                              void* d_out, int out_size, void* d_ws, size_t ws_size,
                              hipStream_t stream) {
    const float* x     = (const float*)d_in[0];
    const float* damp  = (const float*)d_in[1];
    const float* decay = (const float*)d_in[2];
    const float* ema   = (const float*)d_in[3];
    const float* proj  = (const float*)d_in[4];
    const float* rw    = (const float*)d_in[5];
    float* out = (float*)d_out;

    // 1024 blocks x 4 waves; 4 blocks/CU (32KB LDS each) — one generation
    dim3 grid(D / DBLK, NCHUNK, B);
    ema_fused<<<grid, 256, 0, stream>>>(x, damp, decay, ema, proj, rw, out);
}

// Round 7
// 265.523 us; speedup vs baseline: 1.0076x; 1.0076x over previous
//
#include <hip/hip_runtime.h>
#include <math.h>

#define L 4096
#define B 8
#define D 1024
#define NH 16
#define COUT 256              // output chunk per block; windback amort 1.5x
#define WB 128                // windback length (q^128 <= 2.4e-6 worst-case)
#define NCHUNK (L / COUT)     // 16
#define BD 8192               // B*D floats between consecutive l
#define DBLK 128              // d-values per block
#define TL 16                 // l-rows per LDS tile (8KB)
#define NBUF 4                // quad-buffered, 3 tiles in flight

#define REP4(F) F(0) F(1) F(2) F(3)

typedef float f2 __attribute__((ext_vector_type(2)));

__device__ __forceinline__ float sigmoidf(float v) {
    return 1.0f / (1.0f + __expf(-v));
}

// ---- packed-f32 head math: 8 heads/thread = 4 v_pk_fma_f32 chains ----
#define UPD(i) s##i = __builtin_elementwise_fma(q##i, s##i, xv2);
#define UPDALL UPD(0) UPD(1) UPD(2) UPD(3)
#define ACC(i) s##i = __builtin_elementwise_fma(q##i, s##i, xv2); \
               y2 = __builtin_elementwise_fma(P##i, s##i, y2);
#define ACCALL ACC(0) ACC(1) ACC(2) ACC(3)

// async global->LDS, 16B/lane, block-wide tile: wave wv stages rows
// 4wv..4wv+3 (2 instrs x 2 rows x 512B contiguous per row pair).
#define GLD16(g, l) __builtin_amdgcn_global_load_lds( \
    (const __attribute__((address_space(1))) unsigned int*)(g), \
    (__attribute__((address_space(3))) unsigned int*)(l), 16, 0, 0)

#define VM(n) asm volatile("s_waitcnt vmcnt(" #n ")" ::: "memory")
#define MEMFENCE asm volatile("" ::: "memory")

// ---------------------------------------------------------------------------
// Round 7: single-lever A/B vs R6 — drop __builtin_nontemporal_store.
// Diagnosis: delivered HBM BW is ~2.05-2.27 TB/s across SEVEN structurally
// different versions (reg-based, LDS dbuf, barrier-free, counted-vmcnt,
// packed math) with outstanding-bytes from 6KB to 128KB/CU — schedule,
// occupancy, and request depth are all ruled out. The only untested factor
// common to every round: nt stores (131MB, 56% of traffic) pushed as 128B
// chunks at 32KB stride from 256 CUs, finely interleaved with reads ->
// continuous DRAM read/write turnaround. Plain stores let L2/MALL
// write-combine the output and batch writebacks, separating the R and W
// streams at the DRAM. Everything else (staging, barriers, EXACT vmcnt
// ladder — plain stores count in vmcnt identically) is byte-identical:
//   windback:       VM(4)
//   output r=0/1/2: VM(4)/VM(20)/VM(36)
//   output r=3..13: VM(52)
//   output r=14/15: VM(50)/VM(48)
// ---------------------------------------------------------------------------
__global__ void __launch_bounds__(256, 4)
ema_fused(const float* __restrict__ x,
          const float* __restrict__ damp,
          const float* __restrict__ decay,
          const float* __restrict__ ema,
          const float* __restrict__ proj,
          const float* __restrict__ rw,
          float* __restrict__ out) {
    const int tid  = threadIdx.x;
    const int lane = tid & 63;
    const int wv   = tid >> 6;            // wave in block: 0..3
    const int h    = lane & 1;            // head half: 0 -> heads 0-7, 1 -> 8-15
    const int dloc = (wv << 5) + (lane >> 1);   // 0..127: d within block
    const int d    = blockIdx.x * DBLK + dloc;
    const int c    = blockIdx.y;          // 0..NCHUNK-1
    const int b    = blockIdx.z;          // 0..7

    __shared__ float lds[NBUF][TL * DBLK];   // 4 x 8KB = 32KB

    const float* dp = damp  + d * NH + h * 8;
    const float* dc = decay + d * NH + h * 8;
    const float* de = ema   + d * NH + h * 8;
    const float* pj = proj  + d * NH + h * 8;

    // ---- per-head state (packed pairs) + projection weights ----
#define DECLQS(i) f2 q##i, s##i;
    REP4(DECLQS)
#define INITQS(i) { \
        q##i.x = 1.0f - sigmoidf(dp[2*(i)])   * sigmoidf(dc[2*(i)]); \
        q##i.y = 1.0f - sigmoidf(dp[2*(i)+1]) * sigmoidf(dc[2*(i)+1]); \
        s##i.x = 0.0f; s##i.y = 0.0f; }
    REP4(INITQS)
#define DECLP(i) f2 P##i;
    REP4(DECLP)
#define INITP(i) { \
        P##i.x = sigmoidf(dp[2*(i)])   * de[2*(i)]   * pj[2*(i)]   * 0.25f; \
        P##i.y = sigmoidf(dp[2*(i)+1]) * de[2*(i)+1] * pj[2*(i)+1] * 0.25f; }
    REP4(INITP)
    // Even lane of pair adds residual; odd contributes 0; xor-1 combine gives
    // both lanes the identical full result y_conv + x*w.
    const float weff = (h == 0) ? rw[d] : 0.0f;

    // drain parameter loads so the GLD queue accounting below is exact
    VM(0); MEMFENCE;

    const int wb = (c > 0) ? WB : 0;
    const int wt = wb / TL;               // 8 or 0 windback tiles
    const int nt = wt + COUT / TL;        // 24 or 16 tiles total

    // block x base (windback start); per-lane staging src:
    // instr covers 2 rows x 128 floats: row = 4wv + (lane>>5), col = (lane&31)*4
    const float* xb = x + (size_t)(c * COUT - wb) * BD + (size_t)b * D
                        + (size_t)blockIdx.x * DBLK;
    const float* gsrc = xb + (size_t)((wv << 2) + (lane >> 5)) * BD
                           + ((lane & 31) << 2);

#define GLD(t) { \
        const float* g_ = gsrc + (size_t)(t) * (TL * BD); \
        float* l_ = &lds[(t) & 3][(wv << 2) * DBLK]; \
        GLD16(g_, l_); \
        GLD16(g_ + 2 * (size_t)BD, l_ + 2 * DBLK); }

    // ---- prologue: 3 tiles in flight ----
    GLD(0) GLD(1) GLD(2)
    MEMFENCE;

    // ---- windback: state update only (no stores -> VM(4) exact) ----
    if (c > 0) {
        for (int t = 0; t < WB / TL; ++t) {
            VM(4);
            __builtin_amdgcn_s_barrier();
            MEMFENCE;
            GLD(t + 3)
            MEMFENCE;
            const float* bp = &lds[t & 3][dloc];
#pragma unroll
            for (int sl = 0; sl < TL; ++sl) {
                float xv = bp[sl * DBLK];
                f2 xv2; xv2.x = xv; xv2.y = xv;
                UPDALL
            }
        }
    }

    // ---- output phase: 16 tiles ----
    float* opb = out + (size_t)(c * COUT) * BD + (size_t)b * D + d;

#define OTILE(r, KWAIT, DOGLD) { \
        KWAIT; \
        __builtin_amdgcn_s_barrier(); \
        MEMFENCE; \
        if (DOGLD) GLD(wt + (r) + 3) \
        MEMFENCE; \
        const float* bp = &lds[(wt + (r)) & 3][dloc]; \
        float* op = opb + (size_t)(r) * (TL * BD); \
        _Pragma("unroll") \
        for (int sl = 0; sl < TL; ++sl) { \
            float xv = bp[sl * DBLK]; \
            f2 xv2; xv2.x = xv; xv2.y = xv; \
            f2 y2;  y2.x = xv * weff; y2.y = 0.0f; \
            ACCALL \
            float y = y2.x + y2.y; \
            y += __shfl_xor(y, 1); \
            op[(size_t)sl * BD] = fmaxf(y, 0.0f); \
        } }

    OTILE(0,  VM(4),  1)
    OTILE(1,  VM(20), 1)
    OTILE(2,  VM(36), 1)
#pragma unroll
    for (int r = 3; r <= 12; ++r) { OTILE(r, VM(52), 1) }
    OTILE(13, VM(52), 0)
    OTILE(14, VM(50), 0)
    OTILE(15, VM(48), 0)
}

// ---------------------------------------------------------------------------
extern "C" void kernel_launch(void* const* d_in, const int* in_sizes, int n_in,
                              void* d_out, int out_size, void* d_ws, size_t ws_size,
                              hipStream_t stream) {
    const float* x     = (const float*)d_in[0];
    const float* damp  = (const float*)d_in[1];
    const float* decay = (const float*)d_in[2];
    const float* ema   = (const float*)d_in[3];
    const float* proj  = (const float*)d_in[4];
    const float* rw    = (const float*)d_in[5];
    float* out = (float*)d_out;

    // 1024 blocks x 4 waves; 4 blocks/CU (32KB LDS each) — one generation
    dim3 grid(D / DBLK, NCHUNK, B);
    ema_fused<<<grid, 256, 0, stream>>>(x, damp, decay, ema, proj, rw, out);
}

// Round 8
// 250.100 us; speedup vs baseline: 1.0698x; 1.0617x over previous
//
#include <hip/hip_runtime.h>
#include <math.h>

#define L 4096
#define B 8
#define D 1024
#define NH 16
#define COUT 256              // output rows per block; windback amort 1.5x
#define WB 128                // windback length (q^128 <= 2.4e-6 worst-case)
#define NCHUNK (L / COUT)     // 16
#define BD 8192               // B*D floats between consecutive l
#define DBLK 512              // d-values per block: 2KB contiguous per l-row
#define TL 8                  // l-rows per LDS tile (16KB)
#define NBUF 4                // quad-buffered (64KB LDS), depth-3 prefetch

#define REP8(F) F(0) F(1) F(2) F(3) F(4) F(5) F(6) F(7)

typedef float f2 __attribute__((ext_vector_type(2)));

__device__ __forceinline__ float sigmoidf(float v) {
    return 1.0f / (1.0f + __expf(-v));
}

// ---- 16 heads per thread as 8 packed-f32 chains (v_pk_fma_f32) ----
#define UPD(i) s##i = __builtin_elementwise_fma(q##i, s##i, xv2);
#define UPDALL UPD(0) UPD(1) UPD(2) UPD(3) UPD(4) UPD(5) UPD(6) UPD(7)
// two y-accumulators to halve the dependent-chain depth
#define ACCA(i) s##i = __builtin_elementwise_fma(q##i, s##i, xv2); \
                yA = __builtin_elementwise_fma(P##i, s##i, yA);
#define ACCB(i) s##i = __builtin_elementwise_fma(q##i, s##i, xv2); \
                yB = __builtin_elementwise_fma(P##i, s##i, yB);
#define ACCALL ACCA(0) ACCB(1) ACCA(2) ACCB(3) ACCA(4) ACCB(5) ACCA(6) ACCB(7)

// async global->LDS, 16B/lane: one instr = 64 lanes x 16B = 1KB contiguous.
#define GLD16(g, l) __builtin_amdgcn_global_load_lds( \
    (const __attribute__((address_space(1))) unsigned int*)(g), \
    (__attribute__((address_space(3))) unsigned int*)(l), 16, 0, 0)

#define VM(n) asm volatile("s_waitcnt vmcnt(" #n ")" ::: "memory")
#define MEMFENCE asm volatile("" ::: "memory")

// ---------------------------------------------------------------------------
// Round 8: WIDE-SEGMENT test (DBLK 128 -> 512). Seven structures all plateau
// at ~2.26 TB/s delivered HBM while the D2D copy ubench does 6.3 TB/s on the
// same 50/50 R/W mix — the only untested difference is spatial shape: 128-d
// blocks touch a 512B segment every 32KB, i.e. the SAME 2 interleave granules
// (granule = l*128 + b*16 + dchunk*2) and a new DRAM page per 512B, for the
// block's whole lifetime. This version gives each block a 2KB-contiguous
// segment per l-row (half the D-row of one batch): 4x channel spread, whole
// DRAM pages per access. Demand bytes IDENTICAL to R6/R7 (same COUT/WB).
//   512 thr (8 waves), 16 heads/thread, no pair-split/shfl.
//   Tile = 8 rows x 2KB; wave wv stages row wv (2 GLD16). NBUF=4 = 64KB.
//   vmcnt ladder (per wave: 2 loads + 8 stores per output tile):
//     windback:        VM(4)
//     output r=0/1/2:  VM(4)/VM(12)/VM(20)
//     output r=3..29:  VM(28)   (GLD while r<=28)
//     output r=30/31:  VM(26)/VM(24)
// ---------------------------------------------------------------------------
__global__ void __launch_bounds__(512, 1)
ema_fused(const float* __restrict__ x,
          const float* __restrict__ damp,
          const float* __restrict__ decay,
          const float* __restrict__ ema,
          const float* __restrict__ proj,
          const float* __restrict__ rw,
          float* __restrict__ out) {
    const int tid  = threadIdx.x;         // 0..511 = d within block
    const int lane = tid & 63;
    const int wv   = tid >> 6;            // wave in block: 0..7
    const int bx   = blockIdx.x;          // 0..1
    const int c    = blockIdx.y;          // 0..NCHUNK-1
    const int b    = blockIdx.z;          // 0..7
    const int d    = bx * DBLK + tid;

    __shared__ float lds[NBUF][TL][DBLK];   // 4 x 16KB = 64KB

    const float* dp = damp  + d * NH;
    const float* dc = decay + d * NH;
    const float* de = ema   + d * NH;
    const float* pj = proj  + d * NH;

    // ---- per-head state (8 packed pairs = 16 heads) + projection ----
#define DECLQS(i) f2 q##i, s##i;
    REP8(DECLQS)
#define INITQS(i) { \
        q##i.x = 1.0f - sigmoidf(dp[2*(i)])   * sigmoidf(dc[2*(i)]); \
        q##i.y = 1.0f - sigmoidf(dp[2*(i)+1]) * sigmoidf(dc[2*(i)+1]); \
        s##i.x = 0.0f; s##i.y = 0.0f; }
    REP8(INITQS)
#define DECLP(i) f2 P##i;
    REP8(DECLP)
#define INITP(i) { \
        P##i.x = sigmoidf(dp[2*(i)])   * de[2*(i)]   * pj[2*(i)]   * 0.25f; \
        P##i.y = sigmoidf(dp[2*(i)+1]) * de[2*(i)+1] * pj[2*(i)+1] * 0.25f; }
    REP8(INITP)
    const float w = rw[d];

    // drain parameter loads so the GLD queue accounting below is exact
    VM(0); MEMFENCE;

    const int wb = (c > 0) ? WB : 0;
    const int wt = wb / TL;               // 16 or 0 windback tiles
    const int nt = wt + COUT / TL;        // 48 or 32 tiles total

    // block x base (windback start); wave wv stages row wv of each tile:
    // 2KB row = 2 x GLD16 (cols 0..255, 256..511), per-lane src +lane*16B
    const float* xb = x + (size_t)(c * COUT - wb) * BD + (size_t)b * D
                        + (size_t)bx * DBLK;

#define GLD(t) { \
        const float* g_ = xb + (size_t)((t) * TL + wv) * BD + (lane << 2); \
        float* l_ = &lds[(t) & 3][wv][0]; \
        GLD16(g_,       l_); \
        GLD16(g_ + 256, l_ + 256); }

    // ---- prologue: 3 tiles in flight ----
    GLD(0) GLD(1) GLD(2)
    MEMFENCE;

    // ---- windback: state update only (no stores -> VM(4) exact) ----
    if (c > 0) {
        for (int t = 0; t < WB / TL; ++t) {
            VM(4);
            __builtin_amdgcn_s_barrier();
            MEMFENCE;
            GLD(t + 3)
            MEMFENCE;
            const float* bp = &lds[t & 3][0][tid];
#pragma unroll
            for (int sl = 0; sl < TL; ++sl) {
                float xv = bp[sl * DBLK];
                f2 xv2; xv2.x = xv; xv2.y = xv;
                UPDALL
            }
        }
    }

    // ---- output phase: 32 tiles ----
    float* opb = out + (size_t)(c * COUT) * BD + (size_t)b * D
                     + (size_t)bx * DBLK + tid;

#define OTILE(r, KWAIT, DOGLD) { \
        KWAIT; \
        __builtin_amdgcn_s_barrier(); \
        MEMFENCE; \
        if (DOGLD) GLD(wt + (r) + 3) \
        MEMFENCE; \
        const float* bp = &lds[(wt + (r)) & 3][0][tid]; \
        float* op = opb + (size_t)(r) * (TL * BD); \
        _Pragma("unroll") \
        for (int sl = 0; sl < TL; ++sl) { \
            float xv = bp[sl * DBLK]; \
            f2 xv2; xv2.x = xv; xv2.y = xv; \
            f2 yA;  yA.x = xv * w; yA.y = 0.0f; \
            f2 yB;  yB.x = 0.0f;  yB.y = 0.0f; \
            ACCALL \
            f2 yt = yA + yB; \
            float y = yt.x + yt.y; \
            op[(size_t)sl * BD] = fmaxf(y, 0.0f); \
        } }

    OTILE(0, VM(4),  1)
    OTILE(1, VM(12), 1)
    OTILE(2, VM(20), 1)
#pragma unroll
    for (int r = 3; r <= 28; ++r) { OTILE(r, VM(28), 1) }
    OTILE(29, VM(28), 0)
    OTILE(30, VM(26), 0)
    OTILE(31, VM(24), 0)
}

// ---------------------------------------------------------------------------
extern "C" void kernel_launch(void* const* d_in, const int* in_sizes, int n_in,
                              void* d_out, int out_size, void* d_ws, size_t ws_size,
                              hipStream_t stream) {
    const float* x     = (const float*)d_in[0];
    const float* damp  = (const float*)d_in[1];
    const float* decay = (const float*)d_in[2];
    const float* ema   = (const float*)d_in[3];
    const float* proj  = (const float*)d_in[4];
    const float* rw    = (const float*)d_in[5];
    float* out = (float*)d_out;

    // 256 blocks x 8 waves = 1 block/CU (64KB LDS each)
    dim3 grid(D / DBLK, NCHUNK, B);
    ema_fused<<<grid, 512, 0, stream>>>(x, damp, decay, ema, proj, rw, out);
}